// Round 1
// baseline (50.915 us; speedup 1.0000x reference)
//
#include <hip/hip_runtime.h>
#include <math.h>

constexpr int kN = 4096;
constexpr int kD = 4;
constexpr int kTJ = 512;               // j-tile staged in LDS
constexpr int kRowsPerWave = 2;
constexpr int kWavesPerBlock = 4;
constexpr int kRowsPerBlock = kRowsPerWave * kWavesPerBlock;  // 8
constexpr int kBlock = 256;

__global__ __launch_bounds__(kBlock)
void kuramoto_kernel(const float* __restrict__ theta,
                     const float* __restrict__ gam,
                     const float* __restrict__ W,
                     const float* __restrict__ alpha,
                     float* __restrict__ out)
{
    __shared__ __align__(16) float sS[kTJ * kD];
    __shared__ __align__(16) float sC[kTJ * kD];

    const int tid  = threadIdx.x;
    const int wave = tid >> 6;
    const int lane = tid & 63;

    const int row0 = blockIdx.x * kRowsPerBlock;   // global row = b*N + i
    const int b    = row0 / kN;
    const float* thetaB = theta + (size_t)b * kN * kD;

    const int wrow0 = row0 + wave * kRowsPerWave;

    float U[kRowsPerWave][kD];
    float V[kRowsPerWave][kD];
    #pragma unroll
    for (int r = 0; r < kRowsPerWave; ++r)
        #pragma unroll
        for (int d = 0; d < kD; ++d) { U[r][d] = 0.f; V[r][d] = 0.f; }

    const float* Wr[kRowsPerWave];
    const float* Ar[kRowsPerWave];
    #pragma unroll
    for (int r = 0; r < kRowsPerWave; ++r) {
        const size_t off = (size_t)(wrow0 + r) * kN;
        Wr[r] = W + off;
        Ar[r] = alpha + off;
    }

    for (int j0 = 0; j0 < kN; j0 += kTJ) {
        __syncthreads();   // protect previous tile's LDS from overwrite
        // Cooperative: stage sin/cos of theta[b, j0:j0+kTJ, :] into LDS.
        #pragma unroll
        for (int e = tid; e < kTJ * kD; e += kBlock) {
            const float v = thetaB[j0 * kD + e];
            float s, c;
            __sincosf(v, &s, &c);
            sS[e] = s;
            sC[e] = c;
        }
        __syncthreads();

        // Lanes stride over j within the tile; W/alpha reads are coalesced.
        #pragma unroll
        for (int jj = lane; jj < kTJ; jj += 64) {
            const float4 sj4 = *reinterpret_cast<const float4*>(&sS[jj * kD]);
            const float4 cj4 = *reinterpret_cast<const float4*>(&sC[jj * kD]);
            const float sj[4] = {sj4.x, sj4.y, sj4.z, sj4.w};
            const float cj[4] = {cj4.x, cj4.y, cj4.z, cj4.w};
            const int j = j0 + jj;
            #pragma unroll
            for (int r = 0; r < kRowsPerWave; ++r) {
                const float w = Wr[r][j];
                const float a = Ar[r][j];
                float sa, ca;
                __sincosf(a, &sa, &ca);
                const float P = w * ca;
                const float Q = w * sa;
                #pragma unroll
                for (int d = 0; d < kD; ++d) {
                    U[r][d] = fmaf(P, sj[d], fmaf(-Q, cj[d], U[r][d]));
                    V[r][d] = fmaf(P, cj[d], fmaf( Q, sj[d], V[r][d]));
                }
            }
        }
    }

    // Wave-wide butterfly reduction of the 16 accumulators per wave.
    #pragma unroll
    for (int m = 1; m < 64; m <<= 1) {
        #pragma unroll
        for (int r = 0; r < kRowsPerWave; ++r)
            #pragma unroll
            for (int d = 0; d < kD; ++d) {
                U[r][d] += __shfl_xor(U[r][d], m, 64);
                V[r][d] += __shfl_xor(V[r][d], m, 64);
            }
    }

    // Epilogue: lane r writes row wrow0+r (constant register indices only).
    #pragma unroll
    for (int r = 0; r < kRowsPerWave; ++r) {
        if (lane == r) {
            const int row = wrow0 + r;
            const float4 t4 = *reinterpret_cast<const float4*>(&theta[(size_t)row * kD]);
            const float4 g4 = *reinterpret_cast<const float4*>(&gam[(size_t)row * kD]);
            const float tv[4] = {t4.x, t4.y, t4.z, t4.w};
            const float gv[4] = {g4.x, g4.y, g4.z, g4.w};
            constexpr float scale = 1.0f / 4096.0f;   // GLOBAL_COUPLING / N
            float x[4];
            float nsq = 0.f;
            #pragma unroll
            for (int d = 0; d < kD; ++d) {
                float si, ci;
                __sincosf(tv[d], &si, &ci);
                const float coup = scale * (ci * U[r][d] - si * V[r][d]);
                x[d] = gv[d] + coup;          // gamma + coupling (drive cancels theta)
                nsq += x[d] * x[d];
            }
            const float inv = 1.0f / fmaxf(sqrtf(nsq), 1e-6f);
            float4 o;
            o.x = x[0] * inv; o.y = x[1] * inv; o.z = x[2] * inv; o.w = x[3] * inv;
            *reinterpret_cast<float4*>(&out[(size_t)row * kD]) = o;
        }
    }
}

extern "C" void kernel_launch(void* const* d_in, const int* in_sizes, int n_in,
                              void* d_out, int out_size, void* d_ws, size_t ws_size,
                              hipStream_t stream) {
    const float* theta = (const float*)d_in[0];   // (B,N,D) f32
    const float* gam   = (const float*)d_in[1];   // (B,N,D) f32
    const float* W     = (const float*)d_in[2];   // (B,N,N) f32
    const float* alpha = (const float*)d_in[3];   // (B,N,N) f32
    float* out = (float*)d_out;                   // (B,N,D) f32

    const int totalRows = in_sizes[0] / kD;       // B*N = 8192
    const int nblocks = totalRows / kRowsPerBlock; // 1024
    kuramoto_kernel<<<nblocks, kBlock, 0, stream>>>(theta, gam, W, alpha, out);
}